// Round 9
// baseline (251.092 us; speedup 1.0000x reference)
//
#include <hip/hip_runtime.h>

#define BS     8192
#define DIM    768
#define NPART  32               // BS / BN column partitions
#define BM     256
#define BN     256
#define BK     32
#define NKT    (DIM / BK)       // 24 k-tiles
#define L1B    128              // loss stage-1 blocks
#define L1R    (BS / L1B)       // rows per stage-1 block (64)

typedef __bf16 bfrag_t __attribute__((ext_vector_type(8)));
typedef float  facc_t  __attribute__((ext_vector_type(4)));
typedef float  f4raw   __attribute__((ext_vector_type(4)));

typedef const __attribute__((address_space(1))) void gv_t;
typedef __attribute__((address_space(3))) void lv_t;

__device__ __forceinline__ void gll16(const void* g, void* l) {
  // async global->LDS DMA, 16B/lane; LDS dest = wave-uniform base + lane*16
  __builtin_amdgcn_global_load_lds((gv_t*)g, (lv_t*)l, 16, 0, 0);
}

__device__ __forceinline__ unsigned short f2bf(float f) {
  union { float f; unsigned u; } v; v.f = f;
  unsigned u = v.u;
  return (unsigned short)((u + 0x7FFFu + ((u >> 16) & 1u)) >> 16);  // RNE
}

// ---------------- prep: bf16 convert (both) + diag. fp32 copies moved to hipMemcpyAsync ----------------
// (R0-R8 wrote float4 copies to out+1 / out+1+NEL: 4-mod-16 addresses -> misaligned
//  16B stores. The D2D memcpy path handles the unaligned destination efficiently.)
__global__ void prep_kernel(const float* __restrict__ nl, const float* __restrict__ cd,
                            unsigned short* __restrict__ nlb, unsigned short* __restrict__ cdb,
                            float* __restrict__ dg) {
  const int lane = threadIdx.x & 63;
  const int wave = threadIdx.x >> 6;
  const int row  = blockIdx.x * 4 + wave;
  const size_t rbase = (size_t)row * DIM;
  const float4* ar = reinterpret_cast<const float4*>(nl + rbase);
  const float4* br = reinterpret_cast<const float4*>(cd + rbase);
  ushort4* ba = reinterpret_cast<ushort4*>(nlb + rbase);
  ushort4* bb = reinterpret_cast<ushort4*>(cdb + rbase);

  float s = 0.f;
#pragma unroll
  for (int i = 0; i < 3; ++i) {                 // 192 float4 per row, 3 per lane
    int idx = lane + 64 * i;
    float4 x = ar[idx];
    float4 y = br[idx];
    ushort4 xb, yb;
    xb.x = f2bf(x.x); xb.y = f2bf(x.y); xb.z = f2bf(x.z); xb.w = f2bf(x.w);
    yb.x = f2bf(y.x); yb.y = f2bf(y.y); yb.z = f2bf(y.z); yb.w = f2bf(y.w);
    ba[idx] = xb;
    bb[idx] = yb;
    s += x.x * y.x + x.y * y.y + x.z * y.z + x.w * y.w;
  }
#pragma unroll
  for (int off = 32; off; off >>= 1) s += __shfl_xor(s, off, 64);
  if (lane == 0) dg[row] = s;
}

// ---------------- 256x256 software-pipelined GEMM (bf16 MFMA) + lse partials ----------------
// R5 kernel VERBATIM (passed, absmax 0.0) except the XCD-swizzle direction: cb/rb
// swapped so each XCD's 32 resident blocks share ONE cb -> B-panel L2-resident.
// Lesson bank: asm-volatile ds_reads + counted lgkm + vmcnt-then-barrier publication
// is the proven-correct combination; C-level reads + raw s_barrier is UNSOUND
// (s_barrier is not an IR-level memory fence -> R6/R7/R8 deterministic corruption).
__global__ __launch_bounds__(512, 2) void gemm_lse_kernel(
    const unsigned short* __restrict__ Abf,
    const unsigned short* __restrict__ Bbf,
    float* __restrict__ pm, float* __restrict__ pl) {
  __shared__ __align__(16) unsigned short LDSU[49152];   // 96 KB: A bufs 0-2, B bufs 0-2

  const int tid  = threadIdx.x;
  const int lane = tid & 63;
  const int wave = tid >> 6;
  const int wm   = wave >> 2;      // 0..1  M half
  const int wn   = wave & 3;       // 0..3  N quarter
  const int l15  = lane & 15;
  const int l4   = lane >> 4;

  // XCD-chunk swizzle: XCD x gets cb in [4x,4x+4), all rb -> B-panel L2-resident.
  unsigned lin = blockIdx.y * 32 + blockIdx.x;
  unsigned swz = (lin & 7) * 128 + (lin >> 3);
  const int cb = swz >> 5;
  const int rb = swz & 31;

  // ---- staging source (inverse-swizzled): LDS unit u <- global(row=2a+b, c8), where
  //      a=u>>3, s=u&7, l=s^(a&7), b=(l>>2)&1, c8=l&3   (R5-verified)
  const int a0_ = tid >> 3, s0_ = tid & 7, l0_ = s0_ ^ (a0_ & 7);
  const int grow = 2 * a0_ + ((l0_ >> 2) & 1);
  const int gc8  = l0_ & 3;
  const unsigned short* srcA0 = Abf + (size_t)(rb * BM + grow) * DIM + gc8 * 8;
  const unsigned short* srcB0 = Bbf + (size_t)(cb * BN + grow) * DIM + gc8 * 8;
  char* dstA0 = (char*)LDSU + tid * 16;
  char* dstB0 = (char*)LDSU + 49152 + tid * 16;

#define STGA(k) do{ gll16(srcA0 + (size_t)(k) * 32,                    dstA0 + ((k) % 3) * 16384); \
                    gll16(srcA0 + (size_t)128 * DIM + (size_t)(k) * 32, dstA0 + ((k) % 3) * 16384 + 8192);}while(0)
#define STGB(k) do{ gll16(srcB0 + (size_t)(k) * 32,                    dstB0 + ((k) % 3) * 16384); \
                    gll16(srcB0 + (size_t)128 * DIM + (size_t)(k) * 32, dstB0 + ((k) % 3) * 16384 + 8192);}while(0)

  // ---- fragment-read addresses: row = (wm*128|wn*64) + t*16 + l15, k-slot c8 = l4
  //      a = row>>1 (a&7 = (l15>>1)&7, invariant in t), phys = ((row&1)<<2|l4) ^ (a&7)
  const unsigned lds32 = (unsigned)(uintptr_t)(void*)&LDSU[0];
  const unsigned physA = ((unsigned)(((l15 & 1) << 2) | l4)) ^ (unsigned)((l15 >> 1) & 7);
  const unsigned abase = lds32 + (unsigned)(wm * 64 + (l15 >> 1)) * 128 + physA * 16;
  const unsigned bbase = lds32 + 49152u + (unsigned)(wn * 32 + (l15 >> 1)) * 128 + physA * 16;

  f4raw afL[4], afH[4], bfE[4], bfO[4];
  facc_t acc[8][4];
#pragma unroll
  for (int mt = 0; mt < 8; ++mt)
#pragma unroll
    for (int nt = 0; nt < 4; ++nt) acc[mt][nt] = (facc_t){0.f, 0.f, 0.f, 0.f};

#define DSR(dst, addr, off) \
  asm volatile("ds_read_b128 %0, %1 offset:%2" : "=v"(dst) : "v"(addr), "n"(off))
#define RD4(ARR, base, off) do{ \
    DSR(ARR[0], base, (off) + 0 * 1024); DSR(ARR[1], base, (off) + 1 * 1024); \
    DSR(ARR[2], base, (off) + 2 * 1024); DSR(ARR[3], base, (off) + 3 * 1024); }while(0)

#define MFMA_PH(AF, BF, half) do{ \
    _Pragma("unroll") \
    for (int m_ = 0; m_ < 4; ++m_) \
      _Pragma("unroll") \
      for (int n_ = 0; n_ < 4; ++n_) \
        acc[(half) * 4 + m_][n_] = __builtin_amdgcn_mfma_f32_16x16x32_bf16( \
            __builtin_bit_cast(bfrag_t, AF[m_]), __builtin_bit_cast(bfrag_t, BF[n_]), \
            acc[(half) * 4 + m_][n_], 0, 0, 0); \
  }while(0)

#define TOPN(n) do{ __builtin_amdgcn_sched_barrier(0); __builtin_amdgcn_s_barrier(); \
    asm volatile("s_waitcnt lgkmcnt(" #n ")"); __builtin_amdgcn_sched_barrier(0); \
    __builtin_amdgcn_s_setprio(1);}while(0)
#define BOT() do{ __builtin_amdgcn_s_setprio(0); __builtin_amdgcn_sched_barrier(0); \
    __builtin_amdgcn_s_barrier();}while(0)
#define BOTVM(n) do{ __builtin_amdgcn_s_setprio(0); __builtin_amdgcn_sched_barrier(0); \
    asm volatile("s_waitcnt vmcnt(" #n ")"); __builtin_amdgcn_sched_barrier(0); \
    __builtin_amdgcn_s_barrier();}while(0)

#define KT(k, BFC, BFN, VMN) do{ \
    /* phase A(k) */ \
    RD4(afH, abase, ((k) % 3) * 16384 + 4096); \
    if ((k) <= 21) STGA((k) + 2); \
    TOPN(4); \
    MFMA_PH(afL, BFC, 0); \
    BOTVM(VMN);                                   /* vmcnt THEN barrier: publish tile k+1 */ \
    /* phase B(k) */ \
    RD4(BFN, bbase, (((k) + 1) % 3) * 16384); \
    RD4(afL, abase, (((k) + 1) % 3) * 16384); \
    if ((k) <= 21) STGB((k) + 2); \
    TOPN(8); \
    MFMA_PH(afH, BFC, 1); \
    BOT(); \
  }while(0)

  // prologue: tiles 0,1 staged; tile0 published (vmcnt(4) then barrier); pre-read bf(0)+afL(0)
  STGA(0); STGB(0); STGA(1); STGB(1);
  __builtin_amdgcn_sched_barrier(0);
  asm volatile("s_waitcnt vmcnt(4)");
  __builtin_amdgcn_sched_barrier(0);
  __builtin_amdgcn_s_barrier();
  RD4(bfE, bbase, 0);
  RD4(afL, abase, 0);

  KT(0,  bfE, bfO, 2); KT(1,  bfO, bfE, 2); KT(2,  bfE, bfO, 2); KT(3,  bfO, bfE, 2);
  KT(4,  bfE, bfO, 2); KT(5,  bfO, bfE, 2); KT(6,  bfE, bfO, 2); KT(7,  bfO, bfE, 2);
  KT(8,  bfE, bfO, 2); KT(9,  bfO, bfE, 2); KT(10, bfE, bfO, 2); KT(11, bfO, bfE, 2);
  KT(12, bfE, bfO, 2); KT(13, bfO, bfE, 2); KT(14, bfE, bfO, 2); KT(15, bfO, bfE, 2);
  KT(16, bfE, bfO, 2); KT(17, bfO, bfE, 2); KT(18, bfE, bfO, 2); KT(19, bfO, bfE, 2);
  KT(20, bfE, bfO, 2); KT(21, bfO, bfE, 2); KT(22, bfE, bfO, 0);

  // k = 23 (buf 2, odd -> current bf = bfO): no further reads/stages
  RD4(afH, abase, 2 * 16384 + 4096);
  TOPN(4);
  MFMA_PH(afL, bfO, 0);
  BOT();
  TOPN(0);
  MFMA_PH(afH, bfO, 1);
  BOT();

  // ---------------- epilogue: row-wise (max, sumexp) over this block's 256 cols ----------------
  float* cm = reinterpret_cast<float*>(LDSU);            // [4][BM] wn-major scratch (4 KB)
  float* cl = reinterpret_cast<float*>(LDSU + 2048);     // byte 4096+, 4 KB
  __syncthreads();
#pragma unroll
  for (int mt = 0; mt < 8; ++mt)
#pragma unroll
    for (int r = 0; r < 4; ++r) {
      float v0 = acc[mt][0][r], v1 = acc[mt][1][r], v2 = acc[mt][2][r], v3 = acc[mt][3][r];
      float m = fmaxf(fmaxf(v0, v1), fmaxf(v2, v3));
      float l = __expf(v0 - m) + __expf(v1 - m) + __expf(v2 - m) + __expf(v3 - m);
#pragma unroll
      for (int mask = 1; mask < 16; mask <<= 1) {   // combine 16 col-subsets (same row)
        float om = __shfl_xor(m, mask, 64);
        float ol = __shfl_xor(l, mask, 64);
        float mn = fmaxf(m, om);
        l = l * __expf(m - mn) + ol * __expf(om - mn);
        m = mn;
      }
      if (l15 == 0) {
        int rl = wm * 128 + mt * 16 + l4 * 4 + r;
        cm[wn * BM + rl] = m;
        cl[wn * BM + rl] = l;
      }
    }
  __syncthreads();
  if (tid < BM) {
    float m0 = cm[tid],          l0 = cl[tid];
    float m1 = cm[BM + tid],     l1 = cl[BM + tid];
    float m2 = cm[2 * BM + tid], l2 = cl[2 * BM + tid];
    float m3 = cm[3 * BM + tid], l3 = cl[3 * BM + tid];
    float mn = fmaxf(fmaxf(m0, m1), fmaxf(m2, m3));
    float ll = l0 * __expf(m0 - mn) + l1 * __expf(m1 - mn) +
               l2 * __expf(m2 - mn) + l3 * __expf(m3 - mn);
    size_t g = (size_t)(rb * BM + tid) * NPART + cb;
    pm[g] = mn;
    pl[g] = ll;
  }

#undef STGA
#undef STGB
#undef DSR
#undef RD4
#undef MFMA_PH
#undef TOPN
#undef BOT
#undef BOTVM
#undef KT
}

// ---------------- loss stage 1: 128 blocks x 64 rows, partial sums ----------------
__global__ void loss_stage1_kernel(const float* __restrict__ pm, const float* __restrict__ pl,
                                   const float* __restrict__ dg, float* __restrict__ partial) {
  const int tid = threadIdx.x;        // 64 threads, one row each
  const int r   = blockIdx.x * L1R + tid;

  const float4* pmr = reinterpret_cast<const float4*>(pm + (size_t)r * NPART);
  const float4* plr = reinterpret_cast<const float4*>(pl + (size_t)r * NPART);

  float m = -1e30f, l = 0.f;
#pragma unroll
  for (int q = 0; q < NPART / 4; ++q) {
    float4 mv = pmr[q];
    float4 lv = plr[q];
#pragma unroll
    for (int k = 0; k < 4; ++k) {
      float m2 = (&mv.x)[k], l2 = (&lv.x)[k];
      float mn = fmaxf(m, m2);
      l = l * __expf(m - mn) + l2 * __expf(m2 - mn);
      m = mn;
    }
  }
  float local = m + __logf(l) - dg[r];

#pragma unroll
  for (int off = 32; off; off >>= 1) local += __shfl_xor(local, off, 64);
  if (tid == 0) partial[blockIdx.x] = local;
}

// ---------------- loss stage 2: reduce 128 partials -> loss ----------------
__global__ void loss_stage2_kernel(const float* __restrict__ partial, float* __restrict__ out) {
  const int tid = threadIdx.x;        // 128 threads
  float v = partial[tid];
#pragma unroll
  for (int off = 32; off; off >>= 1) v += __shfl_xor(v, off, 64);
  __shared__ float red[2];
  if ((tid & 63) == 0) red[tid >> 6] = v;
  __syncthreads();
  if (tid == 0) out[0] = (red[0] + red[1]) / (float)BS;
}

extern "C" void kernel_launch(void* const* d_in, const int* in_sizes, int n_in,
                              void* d_out, int out_size, void* d_ws, size_t ws_size,
                              hipStream_t stream) {
  const float* nl = (const float*)d_in[0];
  const float* cd = (const float*)d_in[1];
  float* out = (float*)d_out;

  const size_t NEL = (size_t)BS * DIM;

  unsigned short* nlb = (unsigned short*)d_ws;       // NEL bf16
  unsigned short* cdb = nlb + NEL;                   // NEL bf16
  float* pm = (float*)(cdb + NEL);                   // BS*NPART
  float* pl = pm + (size_t)BS * NPART;               // BS*NPART
  float* dg = pl + (size_t)BS * NPART;               // BS
  float* partial = dg + BS;                          // L1B

  // out = [loss, code_vec copy, nl_vec copy]
  prep_kernel<<<BS / 4, 256, 0, stream>>>(nl, cd, nlb, cdb, dg);
  hipMemcpyAsync(out + 1,       cd, NEL * sizeof(float), hipMemcpyDeviceToDevice, stream);
  hipMemcpyAsync(out + 1 + NEL, nl, NEL * sizeof(float), hipMemcpyDeviceToDevice, stream);
  gemm_lse_kernel<<<dim3(32, 32), 512, 0, stream>>>(nlb, cdb, pm, pl);
  loss_stage1_kernel<<<L1B, 64, 0, stream>>>(pm, pl, dg, partial);
  loss_stage2_kernel<<<1, 128, 0, stream>>>(partial, out);
}

// Round 10
// 228.517 us; speedup vs baseline: 1.0988x; 1.0988x over previous
//
#include <hip/hip_runtime.h>

#define BS     8192
#define DIM    768
#define NEL    ((size_t)BS * DIM)
#define NPART  16
#define BM     128
#define BN     128
#define BK     64
#define PCOLS  (BS / NPART)     // 512 cols per partition
#define NJT    (PCOLS / BN)     // 4 col-tiles per block
#define NKT    (DIM / BK)       // 12 k-tiles
#define L1B    128              // loss stage-1 blocks
#define L1R    (BS / L1B)       // rows per stage-1 block (64)

typedef __bf16 bfrag_t __attribute__((ext_vector_type(8)));
typedef float  facc_t  __attribute__((ext_vector_type(4)));

typedef const __attribute__((address_space(1))) void gv_t;
typedef __attribute__((address_space(3))) void lv_t;

__device__ __forceinline__ void gll16(const void* g, void* l) {
  // async global->LDS DMA, 16B/lane; LDS dest = wave-uniform base + lane*16
  __builtin_amdgcn_global_load_lds((gv_t*)g, (lv_t*)l, 16, 0, 0);
}

__device__ __forceinline__ unsigned short f2bf(float f) {
  union { float f; unsigned u; } v; v.f = f;
  unsigned u = v.u;
  return (unsigned short)((u + 0x7FFFu + ((u >> 16) & 1u)) >> 16);  // RNE
}

// ---------------- fused prep: bf16 convert (both), diag, ALIGNED fp32 copy-out ----------------
// out layout: out[0]=loss, out[1..NEL]=cd copy, out[NEL+1..2NEL]=nl copy.
// dst base out+1 is 4-mod-16 — R0-R9 did misaligned float4 stores (or misaligned D2D
// memcpy, R9) and paid ~4x roofline. Fix: shift the SOURCE. Aligned dst vec at element
// 4f (f>=1) = {src[4f-1], v.x, v.y, v.z}; src[4f-1] = __shfl_up(v.w,1) (lane 0: one
// scalar load). Head (d=1..3) and seams (d=NEL, d=2NEL) written scalar by the f==0 lane.
__global__ void prep_kernel(const float* __restrict__ nl, const float* __restrict__ cd,
                            float* __restrict__ out,
                            unsigned short* __restrict__ nlb, unsigned short* __restrict__ cdb,
                            float* __restrict__ dg) {
  const int lane = threadIdx.x & 63;
  const int wave = threadIdx.x >> 6;
  const int row  = blockIdx.x * 4 + wave;
  const size_t fbase = (size_t)row * (DIM / 4);      // float4 index base (192/row)
  const float4* ar = reinterpret_cast<const float4*>(nl);
  const float4* br = reinterpret_cast<const float4*>(cd);
  ushort4* ba = reinterpret_cast<ushort4*>(nlb);
  ushort4* bb = reinterpret_cast<ushort4*>(cdb);
  float4* ov = reinterpret_cast<float4*>(out);       // out base is 16B-aligned

  float s = 0.f;
#pragma unroll
  for (int i = 0; i < 3; ++i) {                 // 192 float4 per row, 3 per lane
    size_t f = fbase + lane + 64 * i;
    float4 x = ar[f];
    float4 y = br[f];
    // bf16 (unchanged -> gemm inputs identical to verified rounds)
    ushort4 xb, yb;
    xb.x = f2bf(x.x); xb.y = f2bf(x.y); xb.z = f2bf(x.z); xb.w = f2bf(x.w);
    yb.x = f2bf(y.x); yb.y = f2bf(y.y); yb.z = f2bf(y.z); yb.w = f2bf(y.w);
    ba[f] = xb;
    bb[f] = yb;
    s += x.x * y.x + x.y * y.y + x.z * y.z + x.w * y.w;

    // aligned copy-out
    float py = __shfl_up(y.w, 1, 64);           // cd[4f-1] for lane>0
    float px = __shfl_up(x.w, 1, 64);           // nl[4f-1] for lane>0
    if (lane == 0 && f > 0) { py = cd[4 * f - 1]; px = nl[4 * f - 1]; }
    if (f > 0) {
      float4 oc; oc.x = py; oc.y = y.x; oc.z = y.y; oc.w = y.z;
      float4 on; on.x = px; on.y = x.x; on.z = x.y; on.w = x.z;
      ov[f] = oc;                                // covers out[4f .. 4f+3]  (cd copy)
      ov[NEL / 4 + f] = on;                      // covers out[NEL+4f .. +3] (nl copy)
    } else {
      out[1] = y.x; out[2] = y.y; out[3] = y.z;              // cd head
      out[NEL + 1] = x.x; out[NEL + 2] = x.y; out[NEL + 3] = x.z;  // nl head
      out[NEL]     = cd[NEL - 1];                            // cd tail seam
      out[2 * NEL] = nl[NEL - 1];                            // nl tail seam
    }
  }
#pragma unroll
  for (int off = 32; off; off >>= 1) s += __shfl_xor(s, off, 64);
  if (lane == 0) dg[row] = s;
}

// ---------------- fused GEMM (bf16 MFMA, global_load_lds staging) + online lse ----------------
// R0 kernel VERBATIM — best measured gemm (131.8 us, absmax 0.0). block: 256 threads
// (4 waves, 2x2 of 64x64), tile 128x128, BK=64. grid: (NPART, BS/BM) = (16, 64).
// LDS: XOR-swizzled, unpadded (required by global_load_lds).
__global__ __launch_bounds__(256, 4) void gemm_lse_kernel(
    const unsigned short* __restrict__ Abf,
    const unsigned short* __restrict__ Bbf,
    float* __restrict__ pm, float* __restrict__ pl) {
  __shared__ __align__(16) unsigned short As[BM * BK];   // 16 KB
  __shared__ __align__(16) unsigned short Bs[BN * BK];   // 16 KB

  const int tid  = threadIdx.x;
  const int lane = tid & 63;
  const int wave = tid >> 6;
  const int wm   = wave >> 1;
  const int wn   = wave & 1;
  const int l15  = lane & 15;
  const int l4   = lane >> 4;
  const int sw   = l15 & 7;        // row-dependent xor for fragment reads
  const int cp   = blockIdx.x;
  const int rb   = blockIdx.y;

  int srow[4], sc8g[4];
#pragma unroll
  for (int t = 0; t < 4; ++t) {
    int u   = wave * 256 + t * 64 + lane;
    srow[t] = u >> 3;
    sc8g[t] = (u & 7) ^ (srow[t] & 7);
  }

  float mrun[4][4], lrun[4][4];
#pragma unroll
  for (int i = 0; i < 4; ++i)
#pragma unroll
    for (int r = 0; r < 4; ++r) { mrun[i][r] = -1e30f; lrun[i][r] = 0.f; }

  for (int jt = 0; jt < NJT; ++jt) {
    facc_t acc[4][4];
#pragma unroll
    for (int mt = 0; mt < 4; ++mt)
#pragma unroll
      for (int nt = 0; nt < 4; ++nt) acc[mt][nt] = (facc_t){0.f, 0.f, 0.f, 0.f};

    for (int kt = 0; kt < NKT; ++kt) {
      __syncthreads();
#pragma unroll
      for (int t = 0; t < 4; ++t) {
        size_t ldso = (size_t)(wave * 256 + t * 64) * 8;  // shorts
        gll16(Abf + (size_t)(rb * BM + srow[t]) * DIM + kt * BK + sc8g[t] * 8, As + ldso);
        gll16(Bbf + (size_t)(cp * PCOLS + jt * BN + srow[t]) * DIM + kt * BK + sc8g[t] * 8, Bs + ldso);
      }
      __syncthreads();

#pragma unroll
      for (int ks = 0; ks < 2; ++ks) {
        const int k8 = ks * 4 + l4;
        bfrag_t af[4], bfv[4];
#pragma unroll
        for (int mt = 0; mt < 4; ++mt) {
          int row = wm * 64 + mt * 16 + l15;
          af[mt] = *reinterpret_cast<const bfrag_t*>(&As[row * BK + (k8 ^ sw) * 8]);
        }
#pragma unroll
        for (int nt = 0; nt < 4; ++nt) {
          int row = wn * 64 + nt * 16 + l15;
          bfv[nt] = *reinterpret_cast<const bfrag_t*>(&Bs[row * BK + (k8 ^ sw) * 8]);
        }
#pragma unroll
        for (int mt = 0; mt < 4; ++mt)
#pragma unroll
          for (int nt = 0; nt < 4; ++nt)
            acc[mt][nt] = __builtin_amdgcn_mfma_f32_16x16x32_bf16(af[mt], bfv[nt], acc[mt][nt], 0, 0, 0);
      }
    }

    // online-lse update (per lane over its own column subset)
#pragma unroll
    for (int mt = 0; mt < 4; ++mt)
#pragma unroll
      for (int r = 0; r < 4; ++r) {
        float v0 = acc[mt][0][r], v1 = acc[mt][1][r], v2 = acc[mt][2][r], v3 = acc[mt][3][r];
        float tm = fmaxf(fmaxf(v0, v1), fmaxf(v2, v3));
        float mn = fmaxf(mrun[mt][r], tm);
        float sc = __expf(mrun[mt][r] - mn);
        lrun[mt][r] = lrun[mt][r] * sc +
                      __expf(v0 - mn) + __expf(v1 - mn) + __expf(v2 - mn) + __expf(v3 - mn);
        mrun[mt][r] = mn;
      }
  }

  // merge across the 16 lanes sharing rows (different column subsets)
#pragma unroll
  for (int mask = 1; mask < 16; mask <<= 1)
#pragma unroll
    for (int mt = 0; mt < 4; ++mt)
#pragma unroll
      for (int r = 0; r < 4; ++r) {
        float om = __shfl_xor(mrun[mt][r], mask, 64);
        float ol = __shfl_xor(lrun[mt][r], mask, 64);
        float mn = fmaxf(mrun[mt][r], om);
        lrun[mt][r] = lrun[mt][r] * __expf(mrun[mt][r] - mn) + ol * __expf(om - mn);
        mrun[mt][r] = mn;
      }

  // combine the two column-half waves via LDS (alias onto As/Bs — done with tiles)
  float* cm = reinterpret_cast<float*>(As);   // [2][BM]
  float* cl = reinterpret_cast<float*>(Bs);   // [2][BM]
  __syncthreads();
  if (l15 == 0) {
#pragma unroll
    for (int mt = 0; mt < 4; ++mt)
#pragma unroll
      for (int r = 0; r < 4; ++r) {
        int rl = wm * 64 + mt * 16 + l4 * 4 + r;
        cm[wn * BM + rl] = mrun[mt][r];
        cl[wn * BM + rl] = lrun[mt][r];
      }
  }
  __syncthreads();
  if (tid < BM) {
    float m0 = cm[tid], l0 = cl[tid];
    float m1 = cm[BM + tid], l1 = cl[BM + tid];
    float mn = fmaxf(m0, m1);
    float ll = l0 * __expf(m0 - mn) + l1 * __expf(m1 - mn);
    size_t g = (size_t)(rb * BM + tid) * NPART + cp;
    pm[g] = mn;
    pl[g] = ll;
  }
}

// ---------------- loss stage 1: 128 blocks x 64 rows, partial sums ----------------
__global__ void loss_stage1_kernel(const float* __restrict__ pm, const float* __restrict__ pl,
                                   const float* __restrict__ dg, float* __restrict__ partial) {
  const int tid = threadIdx.x;        // 64 threads, one row each
  const int r   = blockIdx.x * L1R + tid;

  const float4* pmr = reinterpret_cast<const float4*>(pm + (size_t)r * NPART);
  const float4* plr = reinterpret_cast<const float4*>(pl + (size_t)r * NPART);

  float m = -1e30f, l = 0.f;
#pragma unroll
  for (int q = 0; q < NPART / 4; ++q) {
    float4 mv = pmr[q];
    float4 lv = plr[q];
#pragma unroll
    for (int k = 0; k < 4; ++k) {
      float m2 = (&mv.x)[k], l2 = (&lv.x)[k];
      float mn = fmaxf(m, m2);
      l = l * __expf(m - mn) + l2 * __expf(m2 - mn);
      m = mn;
    }
  }
  float local = m + __logf(l) - dg[r];

  // wave reduce (64 threads = 1 wave)
#pragma unroll
  for (int off = 32; off; off >>= 1) local += __shfl_xor(local, off, 64);
  if (tid == 0) partial[blockIdx.x] = local;
}

// ---------------- loss stage 2: reduce 128 partials -> loss ----------------
__global__ void loss_stage2_kernel(const float* __restrict__ partial, float* __restrict__ out) {
  const int tid = threadIdx.x;        // 128 threads
  float v = partial[tid];
#pragma unroll
  for (int off = 32; off; off >>= 1) v += __shfl_xor(v, off, 64);
  __shared__ float red[2];
  if ((tid & 63) == 0) red[tid >> 6] = v;
  __syncthreads();
  if (tid == 0) out[0] = (red[0] + red[1]) / (float)BS;
}

extern "C" void kernel_launch(void* const* d_in, const int* in_sizes, int n_in,
                              void* d_out, int out_size, void* d_ws, size_t ws_size,
                              hipStream_t stream) {
  const float* nl = (const float*)d_in[0];
  const float* cd = (const float*)d_in[1];
  float* out = (float*)d_out;

  unsigned short* nlb = (unsigned short*)d_ws;       // NEL bf16
  unsigned short* cdb = nlb + NEL;                   // NEL bf16
  float* pm = (float*)(cdb + NEL);                   // BS*NPART
  float* pl = pm + (size_t)BS * NPART;               // BS*NPART
  float* dg = pl + (size_t)BS * NPART;               // BS
  float* partial = dg + BS;                          // L1B

  // out = [loss, code_vec copy, nl_vec copy]
  prep_kernel<<<BS / 4, 256, 0, stream>>>(nl, cd, out, nlb, cdb, dg);
  gemm_lse_kernel<<<dim3(NPART, BS / BM), 256, 0, stream>>>(nlb, cdb, pm, pl);
  loss_stage1_kernel<<<L1B, 64, 0, stream>>>(pm, pl, dg, partial);
  loss_stage2_kernel<<<1, 128, 0, stream>>>(partial, out);
}